// Round 6
// baseline (34.286 us; speedup 1.0000x reference)
//
#include <hip/hip_runtime.h>

#define VOCAB 32000
#define EDIM  128
#define QN    32
#define DN    256
#define NK    11

typedef __attribute__((ext_vector_type(8))) short bf16x8;
typedef __attribute__((ext_vector_type(4))) float f32x4;

#define EXP2F(x) __builtin_amdgcn_exp2f(x)

// RNE float -> bf16
static __device__ inline unsigned short f2bf(float f) {
    unsigned u = __float_as_uint(f);
    return (unsigned short)((u + 0x7fff + ((u >> 16) & 1)) >> 16);
}

// ---------------- pre-pass: L2-normalize rows + convert to bf16 table ----------------
__global__ __launch_bounds__(256) void norm_bf16_kernel(const float* __restrict__ emb,
                                                        unsigned int* __restrict__ nbf) {
    int lane = threadIdx.x & 63;
    int row  = blockIdx.x * 4 + (threadIdx.x >> 6);
    const float2* p = (const float2*)(emb + (size_t)row * EDIM);
    float2 v = p[lane];
    float s = v.x * v.x + v.y * v.y;
    #pragma unroll
    for (int off = 32; off; off >>= 1) s += __shfl_xor(s, off);
    float inv = 1.0f / sqrtf(s);
    unsigned int packed = ((unsigned)f2bf(v.y * inv) << 16) | f2bf(v.x * inv);
    nbf[(size_t)row * (EDIM / 2) + lane] = packed;
}

// ---- DPP 16-lane sum ----
template <int CTRL>
static __device__ inline float dpp_add(float x) {
    int y = __builtin_amdgcn_update_dpp(0, __float_as_int(x), CTRL, 0xF, 0xF, true);
    return x + __int_as_float(y);
}
static __device__ inline float sum16(float x) {
    x = dpp_add<0xB1>(x);    // quad_perm xor 1
    x = dpp_add<0x4E>(x);    // quad_perm xor 2
    x = dpp_add<0x124>(x);   // row_ror:4
    x = dpp_add<0x128>(x);   // row_ror:8
    return x;
}

// ---------------- main: 1 wave = (batch, qtile, 32-doc span); ALL gathers up front ----
__global__ __launch_bounds__(256, 4) void knrm_mfma(const int* __restrict__ qtok,
                                                    const int* __restrict__ dtok,
                                                    const unsigned short* __restrict__ nbf,
                                                    float* __restrict__ part) {
    const float INV_SQRT_2PI = 0.3989422804014327f;
    // chain constants: c_m = exp(20*mu_m - 2)
    const float CCH[9] = {8886110.5f, 162754.797f, 2980.95799f, 54.5981500f, 1.0f,
                          0.0183156389f, 3.35462628e-4f, 6.14421235e-6f, 1.12535175e-7f};

    int task = blockIdx.x * 4 + (threadIdx.x >> 6);
    int lane = threadIdx.x & 63;
    int b     = task >> 4;
    int qtile = (task >> 3) & 1;
    int dspan = task & 7;
    int lr = lane & 15, lg = lane >> 4;

    const int* qt_p = qtok + b * QN + qtile * 16;
    const int* dt_p = dtok + b * DN + dspan * 32;

    // ---- token loads (all independent) ----
    int qtokA = qt_p[lr];
    int td0   = dt_p[lr];
    int td1   = dt_p[16 + lr];
    int qtr0 = qt_p[lg * 4 + 0];
    int qtr1 = qt_p[lg * 4 + 1];
    int qtr2 = qt_p[lg * 4 + 2];
    int qtr3 = qt_p[lg * 4 + 3];

    // ---- issue ALL 12 row gathers back-to-back (max MLP, single wait at use) ----
    const unsigned short* baseA = nbf + (size_t)qtokA * EDIM + lg * 8;
    const unsigned short* base0 = nbf + (size_t)td0   * EDIM + lg * 8;
    const unsigned short* base1 = nbf + (size_t)td1   * EDIM + lg * 8;
    bf16x8 A0 = *(const bf16x8*)(baseA);
    bf16x8 A1 = *(const bf16x8*)(baseA + 32);
    bf16x8 A2 = *(const bf16x8*)(baseA + 64);
    bf16x8 A3 = *(const bf16x8*)(baseA + 96);
    bf16x8 B00 = *(const bf16x8*)(base0);
    bf16x8 B01 = *(const bf16x8*)(base0 + 32);
    bf16x8 B02 = *(const bf16x8*)(base0 + 64);
    bf16x8 B03 = *(const bf16x8*)(base0 + 96);
    bf16x8 B10 = *(const bf16x8*)(base1);
    bf16x8 B11 = *(const bf16x8*)(base1 + 32);
    bf16x8 B12 = *(const bf16x8*)(base1 + 64);
    bf16x8 B13 = *(const bf16x8*)(base1 + 96);

    float kacc[4][NK];
    #pragma unroll
    for (int r = 0; r < 4; ++r)
        #pragma unroll
        for (int k = 0; k < NK; ++k) kacc[r][k] = 0.0f;
    int qtr[4] = {qtr0, qtr1, qtr2, qtr3};

    // ---- tile 0 ----
    {
        f32x4 acc = {0.0f, 0.0f, 0.0f, 0.0f};
        acc = __builtin_amdgcn_mfma_f32_16x16x32_bf16(A0, B00, acc, 0, 0, 0);
        acc = __builtin_amdgcn_mfma_f32_16x16x32_bf16(A1, B01, acc, 0, 0, 0);
        acc = __builtin_amdgcn_mfma_f32_16x16x32_bf16(A2, B02, acc, 0, 0, 0);
        acc = __builtin_amdgcn_mfma_f32_16x16x32_bf16(A3, B03, acc, 0, 0, 0);
        float sc = (td0 > 0) ? INV_SQRT_2PI : 0.0f;
        #pragma unroll
        for (int r = 0; r < 4; ++r) {
            float t = acc[r];
            kacc[r][0] += (td0 == qtr[r]) ? sc : 0.0f;
            float s   = fabsf(t);
            float scP = (t >= 0.0f) ? sc : 0.0f;
            float scN = sc - scP;
            float d   = s - 0.9f;
            float g   = EXP2F(d * d * -72.1347520f);   // exp(-50(s-0.9)^2)
            float E   = EXP2F(s * -28.8539008f);       // exp(-20s)
            #pragma unroll
            for (int m = 1; m <= 10; ++m) {
                kacc[r][m]      = fmaf(g, scP, kacc[r][m]);
                kacc[r][11 - m] = fmaf(g, scN, kacc[r][11 - m]);
                if (m < 10) g = g * E * CCH[m - 1];
            }
        }
    }
    // ---- tile 1 ----
    {
        f32x4 acc = {0.0f, 0.0f, 0.0f, 0.0f};
        acc = __builtin_amdgcn_mfma_f32_16x16x32_bf16(A0, B10, acc, 0, 0, 0);
        acc = __builtin_amdgcn_mfma_f32_16x16x32_bf16(A1, B11, acc, 0, 0, 0);
        acc = __builtin_amdgcn_mfma_f32_16x16x32_bf16(A2, B12, acc, 0, 0, 0);
        acc = __builtin_amdgcn_mfma_f32_16x16x32_bf16(A3, B13, acc, 0, 0, 0);
        float sc = (td1 > 0) ? INV_SQRT_2PI : 0.0f;
        #pragma unroll
        for (int r = 0; r < 4; ++r) {
            float t = acc[r];
            kacc[r][0] += (td1 == qtr[r]) ? sc : 0.0f;
            float s   = fabsf(t);
            float scP = (t >= 0.0f) ? sc : 0.0f;
            float scN = sc - scP;
            float d   = s - 0.9f;
            float g   = EXP2F(d * d * -72.1347520f);
            float E   = EXP2F(s * -28.8539008f);
            #pragma unroll
            for (int m = 1; m <= 10; ++m) {
                kacc[r][m]      = fmaf(g, scP, kacc[r][m]);
                kacc[r][11 - m] = fmaf(g, scN, kacc[r][11 - m]);
                if (m < 10) g = g * E * CCH[m - 1];
            }
        }
    }

    // ---- DPP reduce over 16 doc-columns; write partial [16 rows][NK] ----
    #pragma unroll
    for (int r = 0; r < 4; ++r)
        #pragma unroll
        for (int k = 0; k < NK; ++k) kacc[r][k] = sum16(kacc[r][k]);

    if (lr == 0) {
        float* dst = part + ((size_t)task * 16 + lg * 4) * NK;
        #pragma unroll
        for (int r = 0; r < 4; ++r)
            #pragma unroll
            for (int k = 0; k < NK; ++k)
                dst[r * NK + k] = kacc[r][k];
    }
}

// ---------------- final: one block per batch, sum 8 dspans + log-pool ----------------
__global__ __launch_bounds__(128) void knrm_reduce(const int* __restrict__ qtok,
                                                   const float* __restrict__ part,
                                                   const float* __restrict__ fcw,
                                                   float* __restrict__ out) {
    __shared__ float red[2];
    int b = blockIdx.x, tid = threadIdx.x;
    const float* p = part + (size_t)b * 16 * 16 * NK;   // 16 tasks x [16][NK]

    float sum = 0.0f;
    for (int i = tid; i < QN * NK; i += 128) {
        int q = i / NK, k = i - q * NK;
        int qt = q >> 4, row = q & 15;
        const float* pb = p + ((qt * 8) * 16 + row) * NK + k;
        float v = 0.0f;
        #pragma unroll
        for (int ds = 0; ds < 8; ++ds) v += pb[ds * 16 * NK];
        float m = (qtok[b * QN + q] > 0) ? 1.0f : 0.0f;
        sum += m * fcw[k] * __logf(fmaxf(v, 1e-10f));
    }
    #pragma unroll
    for (int off = 32; off; off >>= 1) sum += __shfl_xor(sum, off);
    if ((tid & 63) == 0) red[tid >> 6] = sum;
    __syncthreads();
    if (tid == 0) out[b] = red[0] + red[1];
}

extern "C" void kernel_launch(void* const* d_in, const int* in_sizes, int n_in,
                              void* d_out, int out_size, void* d_ws, size_t ws_size,
                              hipStream_t stream) {
    const int*   qtok = (const int*)d_in[0];
    const int*   dtok = (const int*)d_in[1];
    const float* emb  = (const float*)d_in[2];
    const float* fcw  = (const float*)d_in[3];
    float* out = (float*)d_out;
    unsigned int* nbf = (unsigned int*)d_ws;                        // 8.192 MB
    float* part = (float*)((char*)d_ws + (size_t)VOCAB * EDIM * 2); // 8192*176 floats

    norm_bf16_kernel<<<VOCAB / 4, 256, 0, stream>>>(emb, nbf);

    int B = in_sizes[0] / QN;                                       // 512
    knrm_mfma<<<B * 4, 256, 0, stream>>>(qtok, dtok, (const unsigned short*)nbf, part);
    knrm_reduce<<<B, 128, 0, stream>>>(qtok, part, fcw, out);
}

// Round 7
// 28.015 us; speedup vs baseline: 1.2239x; 1.2239x over previous
//
#include <hip/hip_runtime.h>

#define VOCAB 32000
#define EDIM  128
#define QN    32
#define DN    256
#define NK    11

typedef __attribute__((ext_vector_type(8))) short bf16x8;
typedef __attribute__((ext_vector_type(4))) float f32x4;

#define EXP2F(x) __builtin_amdgcn_exp2f(x)

// RNE float -> bf16
static __device__ inline unsigned short f2bf(float f) {
    unsigned u = __float_as_uint(f);
    return (unsigned short)((u + 0x7fff + ((u >> 16) & 1)) >> 16);
}

// ---------------- pre-pass: L2-normalize rows + convert to bf16 table ----------------
__global__ __launch_bounds__(256) void norm_bf16_kernel(const float* __restrict__ emb,
                                                        unsigned int* __restrict__ nbf) {
    int lane = threadIdx.x & 63;
    int row  = blockIdx.x * 4 + (threadIdx.x >> 6);
    const float2* p = (const float2*)(emb + (size_t)row * EDIM);
    float2 v = p[lane];
    float s = v.x * v.x + v.y * v.y;
    #pragma unroll
    for (int off = 32; off; off >>= 1) s += __shfl_xor(s, off);
    float inv = 1.0f / sqrtf(s);
    unsigned int packed = ((unsigned)f2bf(v.y * inv) << 16) | f2bf(v.x * inv);
    nbf[(size_t)row * (EDIM / 2) + lane] = packed;
}

// ---- DPP 16-lane sum ----
template <int CTRL>
static __device__ inline float dpp_add(float x) {
    int y = __builtin_amdgcn_update_dpp(0, __float_as_int(x), CTRL, 0xF, 0xF, true);
    return x + __int_as_float(y);
}
static __device__ inline float sum16(float x) {
    x = dpp_add<0xB1>(x);    // quad_perm xor 1
    x = dpp_add<0x4E>(x);    // quad_perm xor 2
    x = dpp_add<0x124>(x);   // row_ror:4
    x = dpp_add<0x128>(x);   // row_ror:8
    return x;
}

// XOR row swizzle: c = 16B-aligned byte column within a 256B row
static __device__ inline int swz(int r, int c) { return c ^ ((r & 7) << 4); }

// ---------------- fused main: one 8-wave block per batch ----------------
// Stage 256 d-rows + 32 q-rows (bf16, swizzled) in LDS once; wave w=(qt,ds)
// computes 16q x 64d via MFMA; in-block log-pool -> out[b].
__global__ __launch_bounds__(512, 2) void knrm_fused(const int* __restrict__ qtok,
                                                     const int* __restrict__ dtok,
                                                     const unsigned short* __restrict__ nbf,
                                                     const float* __restrict__ fcw,
                                                     float* __restrict__ out) {
    __shared__ __align__(16) unsigned short dbuf[DN * EDIM];  // 64 KB
    __shared__ __align__(16) unsigned short qbuf[QN * EDIM];  // 8 KB; overlaid by part[8][16][NK]
    __shared__ int   dtokS[DN];
    __shared__ int   qtokS[QN];
    __shared__ float redS[8];

    const float INV_SQRT_2PI = 0.3989422804014327f;
    // chain constants c_m = exp(20*mu_m - 2)
    const float CCH[9] = {8886110.5f, 162754.797f, 2980.95799f, 54.5981500f, 1.0f,
                          0.0183156389f, 3.35462628e-4f, 6.14421235e-6f, 1.12535175e-7f};

    int b = blockIdx.x, tid = threadIdx.x;
    int w = tid >> 6, lane = tid & 63;
    int lr = lane & 15, lg = lane >> 4;

    if (tid < DN) dtokS[tid] = dtok[b * DN + tid];
    else if (tid < DN + QN) qtokS[tid - DN] = qtok[b * QN + (tid - DN)];
    __syncthreads();

    // ---- stage rows: 16 consecutive lanes cover one 256B row (coalesced), swizzled LDS ----
    {
        int j = lr, sub = lane >> 4;                  // slot, row-within-quad
        int qr = (w << 2) + sub;                      // q rows: 4 per wave
        int qtv = qtokS[qr];
        bf16x8 qv = *(const bf16x8*)(nbf + (size_t)qtv * EDIM + j * 8);
        *(bf16x8*)((char*)qbuf + qr * 256 + swz(qr, j * 16)) = qv;
        #pragma unroll
        for (int it = 0; it < 8; ++it) {              // d rows: 32 per wave
            int r = (w << 5) + (it << 2) + sub;
            int tok = dtokS[r];
            bf16x8 v = *(const bf16x8*)(nbf + (size_t)tok * EDIM + j * 8);
            *(bf16x8*)((char*)dbuf + r * 256 + swz(r, j * 16)) = v;
        }
    }
    __syncthreads();

    int qt = w & 1, ds = w >> 1;

    // ---- A fragments (q rows) from LDS ----
    bf16x8 A0, A1, A2, A3;
    {
        int qr = (qt << 4) + lr;
        const char* qb = (const char*)qbuf + qr * 256;
        A0 = *(const bf16x8*)(qb + swz(qr, lg * 16));
        A1 = *(const bf16x8*)(qb + swz(qr, lg * 16 + 64));
        A2 = *(const bf16x8*)(qb + swz(qr, lg * 16 + 128));
        A3 = *(const bf16x8*)(qb + swz(qr, lg * 16 + 192));
    }
    int qtr[4];
    #pragma unroll
    for (int r = 0; r < 4; ++r) qtr[r] = qtokS[(qt << 4) + (lg << 2) + r];
    __syncthreads();                                   // qbuf now free for overlay

    float* part = (float*)qbuf;                        // [8][16][NK] = 5.6 KB

    float kacc[4][NK];
    #pragma unroll
    for (int r = 0; r < 4; ++r)
        #pragma unroll
        for (int k = 0; k < NK; ++k) kacc[r][k] = 0.0f;

    #pragma unroll
    for (int t = 0; t < 4; ++t) {
        int dr = (ds << 6) + (t << 4) + lr;
        const char* db = (const char*)dbuf + dr * 256;
        bf16x8 B0 = *(const bf16x8*)(db + swz(dr, lg * 16));
        bf16x8 B1 = *(const bf16x8*)(db + swz(dr, lg * 16 + 64));
        bf16x8 B2 = *(const bf16x8*)(db + swz(dr, lg * 16 + 128));
        bf16x8 B3 = *(const bf16x8*)(db + swz(dr, lg * 16 + 192));
        int tcur = dtokS[dr];

        f32x4 acc = {0.0f, 0.0f, 0.0f, 0.0f};
        acc = __builtin_amdgcn_mfma_f32_16x16x32_bf16(A0, B0, acc, 0, 0, 0);
        acc = __builtin_amdgcn_mfma_f32_16x16x32_bf16(A1, B1, acc, 0, 0, 0);
        acc = __builtin_amdgcn_mfma_f32_16x16x32_bf16(A2, B2, acc, 0, 0, 0);
        acc = __builtin_amdgcn_mfma_f32_16x16x32_bf16(A3, B3, acc, 0, 0, 0);

        float sc = (tcur > 0) ? INV_SQRT_2PI : 0.0f;
        #pragma unroll
        for (int r = 0; r < 4; ++r) {
            float t2 = acc[r];
            kacc[r][0] += (tcur == qtr[r]) ? sc : 0.0f;   // K0: exact token match
            float s   = fabsf(t2);
            float scP = (t2 >= 0.0f) ? sc : 0.0f;
            float scN = sc - scP;
            float d   = s - 0.9f;
            float g   = EXP2F(d * d * -72.1347520f);      // exp(-50(s-0.9)^2)
            float E   = EXP2F(s * -28.8539008f);          // exp(-20s)
            #pragma unroll
            for (int m = 1; m <= 10; ++m) {
                kacc[r][m]      = fmaf(g, scP, kacc[r][m]);
                kacc[r][11 - m] = fmaf(g, scN, kacc[r][11 - m]);
                if (m < 10) g = g * E * CCH[m - 1];
            }
        }
    }

    // ---- DPP reduce over doc-columns; write wave partial [16][NK] ----
    #pragma unroll
    for (int r = 0; r < 4; ++r)
        #pragma unroll
        for (int k = 0; k < NK; ++k) kacc[r][k] = sum16(kacc[r][k]);

    if (lr == 0) {
        float* pw = part + w * (16 * NK) + (lg * 4) * NK;
        #pragma unroll
        for (int r = 0; r < 4; ++r)
            #pragma unroll
            for (int k = 0; k < NK; ++k)
                pw[r * NK + k] = kacc[r][k];
    }
    __syncthreads();

    // ---- combine 4 dspans, log-pool, weighted sum -> out[b] ----
    float total = 0.0f;
    if (tid < QN * NK) {
        int q = tid / NK, k = tid - (tid / NK) * NK;
        int qt2 = q >> 4, row = q & 15;
        const float* pb = part + qt2 * (16 * NK) + row * NK + k;
        float v = pb[0] + pb[2 * 16 * NK] + pb[4 * 16 * NK] + pb[6 * 16 * NK];
        float m = (qtokS[q] > 0) ? 1.0f : 0.0f;
        total = m * fcw[k] * __logf(fmaxf(v, 1e-10f));
    }
    #pragma unroll
    for (int off = 32; off; off >>= 1) total += __shfl_xor(total, off);
    if (lane == 0) redS[w] = total;
    __syncthreads();
    if (tid == 0) {
        float s = 0.0f;
        #pragma unroll
        for (int i = 0; i < 8; ++i) s += redS[i];
        out[b] = s;
    }
}

extern "C" void kernel_launch(void* const* d_in, const int* in_sizes, int n_in,
                              void* d_out, int out_size, void* d_ws, size_t ws_size,
                              hipStream_t stream) {
    const int*   qtok = (const int*)d_in[0];
    const int*   dtok = (const int*)d_in[1];
    const float* emb  = (const float*)d_in[2];
    const float* fcw  = (const float*)d_in[3];
    float* out = (float*)d_out;
    unsigned int* nbf = (unsigned int*)d_ws;   // 8.192 MB bf16 table

    norm_bf16_kernel<<<VOCAB / 4, 256, 0, stream>>>(emb, nbf);

    int B = in_sizes[0] / QN;                  // 512
    knrm_fused<<<B, 512, 0, stream>>>(qtok, dtok, (const unsigned short*)nbf, fcw, out);
}

// Round 8
// 23.584 us; speedup vs baseline: 1.4538x; 1.1879x over previous
//
#include <hip/hip_runtime.h>
#include <hip/hip_bf16.h>

#define VOCAB 32000
#define EDIM  128
#define QN    32
#define DN    256
#define NK    11

typedef __attribute__((ext_vector_type(8))) short bf16x8;
typedef __attribute__((ext_vector_type(4))) float f32x4;

#define EXP2F(x) __builtin_amdgcn_exp2f(x)

// ---- DPP 16-lane sum (within each aligned group of 16 lanes) ----
template <int CTRL>
static __device__ inline float dpp_add(float x) {
    int y = __builtin_amdgcn_update_dpp(0, __float_as_int(x), CTRL, 0xF, 0xF, true);
    return x + __int_as_float(y);
}
static __device__ inline float sum16(float x) {
    x = dpp_add<0xB1>(x);    // quad_perm xor 1
    x = dpp_add<0x4E>(x);    // quad_perm xor 2
    x = dpp_add<0x124>(x);   // row_ror:4
    x = dpp_add<0x128>(x);   // row_ror:8
    return x;
}

// XOR row swizzle: c = 16B-aligned byte column within a 256B (bf16) row
static __device__ inline int swz(int r, int c) { return c ^ ((r & 7) << 4); }

static __device__ inline bf16x8 pack8(float4 a, float4 b) {
    union { bf16x8 v; __hip_bfloat16 h[8]; } u;
    u.h[0] = __float2bfloat16(a.x); u.h[1] = __float2bfloat16(a.y);
    u.h[2] = __float2bfloat16(a.z); u.h[3] = __float2bfloat16(a.w);
    u.h[4] = __float2bfloat16(b.x); u.h[5] = __float2bfloat16(b.y);
    u.h[6] = __float2bfloat16(b.z); u.h[7] = __float2bfloat16(b.w);
    return u.v;
}

// ---------------- single fused kernel: one 8-wave block per batch ----------------
// Stage raw emb rows (fp32 -> bf16, swizzled LDS) + per-row inv-norms inline;
// MFMA on raw bf16; normalize the accumulator by invq*invd; kernel-eval; log-pool.
__global__ __launch_bounds__(512, 2) void knrm_fused(const int* __restrict__ qtok,
                                                     const int* __restrict__ dtok,
                                                     const float* __restrict__ emb,
                                                     const float* __restrict__ fcw,
                                                     float* __restrict__ out) {
    __shared__ __align__(16) unsigned short dbuf[DN * EDIM];  // 64 KB
    __shared__ __align__(16) unsigned short qbuf[QN * EDIM];  // 8 KB; overlaid by part[8][16][NK]
    __shared__ int   dtokS[DN];
    __shared__ int   qtokS[QN];
    __shared__ float invS[DN + QN];                           // invd[0..255], invq[256..287]
    __shared__ float redS[8];

    const float INV_SQRT_2PI = 0.3989422804014327f;
    // chain constants c_m = exp(20*mu_m - 2)
    const float CCH[9] = {8886110.5f, 162754.797f, 2980.95799f, 54.5981500f, 1.0f,
                          0.0183156389f, 3.35462628e-4f, 6.14421235e-6f, 1.12535175e-7f};

    int b = blockIdx.x, tid = threadIdx.x;
    int w = tid >> 6, lane = tid & 63;
    int lr = lane & 15, lg = lane >> 4;

    if (tid < DN) dtokS[tid] = dtok[b * DN + tid];
    else if (tid < DN + QN) qtokS[tid - DN] = qtok[b * QN + (tid - DN)];
    __syncthreads();

    // ---- stage rows: 16 lanes x 32B cover one 512B fp32 row; inline norm; bf16 to LDS ----
    {
        int j = lr, sub = lg;                         // slot in row, row-within-quad
        // q rows: 4 per wave
        {
            int qr = (w << 2) + sub;
            int tok = qtokS[qr];
            const float4* src = (const float4*)(emb + (size_t)tok * EDIM) + j * 2;
            float4 v0 = src[0], v1 = src[1];
            float ss = v0.x * v0.x + v0.y * v0.y + v0.z * v0.z + v0.w * v0.w;
            ss = fmaf(v1.x, v1.x, ss); ss = fmaf(v1.y, v1.y, ss);
            ss = fmaf(v1.z, v1.z, ss); ss = fmaf(v1.w, v1.w, ss);
            float tot = sum16(ss);
            if (j == 0) invS[DN + qr] = 1.0f / sqrtf(tot);
            *(bf16x8*)((char*)qbuf + qr * 256 + swz(qr, j * 16)) = pack8(v0, v1);
        }
        // d rows: 32 per wave
        #pragma unroll
        for (int it = 0; it < 8; ++it) {
            int r = (w << 5) + (it << 2) + sub;
            int tok = dtokS[r];
            const float4* src = (const float4*)(emb + (size_t)tok * EDIM) + j * 2;
            float4 v0 = src[0], v1 = src[1];
            float ss = v0.x * v0.x + v0.y * v0.y + v0.z * v0.z + v0.w * v0.w;
            ss = fmaf(v1.x, v1.x, ss); ss = fmaf(v1.y, v1.y, ss);
            ss = fmaf(v1.z, v1.z, ss); ss = fmaf(v1.w, v1.w, ss);
            float tot = sum16(ss);
            if (j == 0) invS[r] = 1.0f / sqrtf(tot);
            *(bf16x8*)((char*)dbuf + r * 256 + swz(r, j * 16)) = pack8(v0, v1);
        }
    }
    __syncthreads();

    int qt = w & 1, ds = w >> 1;

    // ---- A fragments (raw q rows) + per-C-row inverse norms ----
    bf16x8 A0, A1, A2, A3;
    {
        int qr = (qt << 4) + lr;
        const char* qb = (const char*)qbuf + qr * 256;
        A0 = *(const bf16x8*)(qb + swz(qr, lg * 16));
        A1 = *(const bf16x8*)(qb + swz(qr, lg * 16 + 64));
        A2 = *(const bf16x8*)(qb + swz(qr, lg * 16 + 128));
        A3 = *(const bf16x8*)(qb + swz(qr, lg * 16 + 192));
    }
    int   qtr[4];
    float invq[4];
    #pragma unroll
    for (int r = 0; r < 4; ++r) {
        int qrow = (qt << 4) + (lg << 2) + r;
        qtr[r]  = qtokS[qrow];
        invq[r] = invS[DN + qrow];
    }
    __syncthreads();                                   // qbuf now free for overlay

    float* part = (float*)qbuf;                        // [8][16][NK] = 5.6 KB

    float kacc[4][NK];
    #pragma unroll
    for (int r = 0; r < 4; ++r)
        #pragma unroll
        for (int k = 0; k < NK; ++k) kacc[r][k] = 0.0f;

    #pragma unroll
    for (int t = 0; t < 4; ++t) {
        int dr = (ds << 6) + (t << 4) + lr;
        const char* db = (const char*)dbuf + dr * 256;
        bf16x8 B0 = *(const bf16x8*)(db + swz(dr, lg * 16));
        bf16x8 B1 = *(const bf16x8*)(db + swz(dr, lg * 16 + 64));
        bf16x8 B2 = *(const bf16x8*)(db + swz(dr, lg * 16 + 128));
        bf16x8 B3 = *(const bf16x8*)(db + swz(dr, lg * 16 + 192));
        int   tcur = dtokS[dr];
        float invd = invS[dr];

        f32x4 acc = {0.0f, 0.0f, 0.0f, 0.0f};
        acc = __builtin_amdgcn_mfma_f32_16x16x32_bf16(A0, B0, acc, 0, 0, 0);
        acc = __builtin_amdgcn_mfma_f32_16x16x32_bf16(A1, B1, acc, 0, 0, 0);
        acc = __builtin_amdgcn_mfma_f32_16x16x32_bf16(A2, B2, acc, 0, 0, 0);
        acc = __builtin_amdgcn_mfma_f32_16x16x32_bf16(A3, B3, acc, 0, 0, 0);

        float sc = (tcur > 0) ? INV_SQRT_2PI : 0.0f;
        #pragma unroll
        for (int r = 0; r < 4; ++r) {
            float t2 = acc[r] * (invq[r] * invd);         // post-MFMA normalization
            kacc[r][0] += (tcur == qtr[r]) ? sc : 0.0f;   // K0: exact token match
            float s   = fabsf(t2);
            float scP = (t2 >= 0.0f) ? sc : 0.0f;
            float scN = sc - scP;
            float d   = s - 0.9f;
            float g   = EXP2F(d * d * -72.1347520f);      // exp(-50(s-0.9)^2)
            float E   = EXP2F(s * -28.8539008f);          // exp(-20s)
            #pragma unroll
            for (int m = 1; m <= 10; ++m) {
                kacc[r][m]      = fmaf(g, scP, kacc[r][m]);
                kacc[r][11 - m] = fmaf(g, scN, kacc[r][11 - m]);
                if (m < 10) g = g * E * CCH[m - 1];
            }
        }
    }

    // ---- DPP reduce over doc-columns; write wave partial [16][NK] ----
    #pragma unroll
    for (int r = 0; r < 4; ++r)
        #pragma unroll
        for (int k = 0; k < NK; ++k) kacc[r][k] = sum16(kacc[r][k]);

    if (lr == 0) {
        float* pw = part + w * (16 * NK) + (lg * 4) * NK;
        #pragma unroll
        for (int r = 0; r < 4; ++r)
            #pragma unroll
            for (int k = 0; k < NK; ++k)
                pw[r * NK + k] = kacc[r][k];
    }
    __syncthreads();

    // ---- combine 4 dspans, log-pool, weighted sum -> out[b] ----
    float total = 0.0f;
    if (tid < QN * NK) {
        int q = tid / NK, k = tid - (tid / NK) * NK;
        int qt2 = q >> 4, row = q & 15;
        const float* pb = part + qt2 * (16 * NK) + row * NK + k;
        float v = pb[0] + pb[2 * 16 * NK] + pb[4 * 16 * NK] + pb[6 * 16 * NK];
        float m = (qtokS[q] > 0) ? 1.0f : 0.0f;
        total = m * fcw[k] * __logf(fmaxf(v, 1e-10f));
    }
    #pragma unroll
    for (int off = 32; off; off >>= 1) total += __shfl_xor(total, off);
    if (lane == 0) redS[w] = total;
    __syncthreads();
    if (tid == 0) {
        float s = 0.0f;
        #pragma unroll
        for (int i = 0; i < 8; ++i) s += redS[i];
        out[b] = s;
    }
}

extern "C" void kernel_launch(void* const* d_in, const int* in_sizes, int n_in,
                              void* d_out, int out_size, void* d_ws, size_t ws_size,
                              hipStream_t stream) {
    const int*   qtok = (const int*)d_in[0];
    const int*   dtok = (const int*)d_in[1];
    const float* emb  = (const float*)d_in[2];
    const float* fcw  = (const float*)d_in[3];
    float* out = (float*)d_out;

    int B = in_sizes[0] / QN;                  // 512
    knrm_fused<<<B, 512, 0, stream>>>(qtok, dtok, emb, fcw, out);
}